// Round 8
// baseline (348.720 us; speedup 1.0000x reference)
//
#include <hip/hip_runtime.h>
#include <hip/hip_bf16.h>

// GraphSAGE 2-layer: bucket-sort CSR build + bf16 MFMA transform-then-aggregate.
// N=100000, E=3.2M, IN=256, H=128, OUT=64.
// Neighbor buffers (t1n/t2n) stored fp8-e4m3 (halved gather traffic).
// GEMM: B resident in LDS in MFMA-FRAGMENT ORDER (conflict-free ds_read_b128,
// immediate offsets), 64-col y-blocks for L1 (32KB LDS -> ~3 blocks/CU),
// A streamed global->reg with convert-then-prefetch pipeline.

typedef unsigned int uint32;
typedef __attribute__((ext_vector_type(8))) short short8;
typedef __attribute__((ext_vector_type(4))) float f32x4;

#define NBMAX 1024     // max buckets (N <= 131072 at 128 nodes/bucket)
#define EPB   8192     // edges per block in bucket count/scatter

#if defined(__has_builtin)
#if __has_builtin(__builtin_amdgcn_cvt_pk_f32_fp8) && __has_builtin(__builtin_amdgcn_cvt_pk_fp8_f32)
#define FP8_HW 1
#endif
#endif
#ifndef FP8_HW
#define FP8_HW 0
#endif

__device__ __forceinline__ unsigned short f2bf(float f) {
    unsigned u = __float_as_uint(f);
    u += 0x7fffu + ((u >> 16) & 1u);      // RNE
    return (unsigned short)(u >> 16);
}
__device__ __forceinline__ uint32 pack2bf(float lo, float hi) {
    return (uint32)f2bf(lo) | ((uint32)f2bf(hi) << 16);
}
__device__ __forceinline__ float bf_lo(uint32 v) { return __uint_as_float(v << 16); }
__device__ __forceinline__ float bf_hi(uint32 v) { return __uint_as_float(v & 0xFFFF0000u); }

// ---- fp8 e4m3 encode/decode ----
__device__ __forceinline__ unsigned char enc8(float v) {
#if FP8_HW
    return (unsigned char)(__builtin_amdgcn_cvt_pk_fp8_f32(v, v, 0, false) & 0xFF);
#else
    float g = v * 0x1p-120f;
    uint32 b = __float_as_uint(g);
    uint32 s = (b >> 24) & 0x80u;
    b &= 0x7fffffffu;
    b += 0x7ffffu + ((b >> 20) & 1u);     // RNE to 3 mantissa bits
    int t = (int)(b >> 20) - 960;
    t = t < 0 ? 0 : (t > 126 ? 126 : t);
    return (unsigned char)(s | (uint32)t);
#endif
}
#if !FP8_HW
__device__ __forceinline__ float dec1(uint32 b) {
    uint32 bits = ((b & 0x80u) << 24) | ((b & 0x7fu) << 20);
    return __uint_as_float(bits) * 0x1p+120f;
}
#endif
__device__ __forceinline__ void dec_u32(uint32 u, float& f0, float& f1, float& f2, float& f3) {
#if FP8_HW
    auto lo = __builtin_amdgcn_cvt_pk_f32_fp8(u, false);
    auto hi = __builtin_amdgcn_cvt_pk_f32_fp8(u, true);
    f0 = lo[0]; f1 = lo[1]; f2 = hi[0]; f3 = hi[1];
#else
    f0 = dec1(u & 0xffu); f1 = dec1((u >> 8) & 0xffu);
    f2 = dec1((u >> 16) & 0xffu); f3 = dec1(u >> 24);
#endif
}

// ---------------- bucket-sort CSR build (bucket = dst >> 7) ----------------
__global__ __launch_bounds__(256) void k_bucket_count(const int* __restrict__ dst, int E,
                                                      int* __restrict__ bcnt) {
    __shared__ int hist[NBMAX];
    for (int i = threadIdx.x; i < NBMAX; i += 256) hist[i] = 0;
    __syncthreads();
    int base = blockIdx.x * EPB;
    #pragma unroll 4
    for (int i = 0; i < EPB / 256; ++i) {
        int e = base + i * 256 + threadIdx.x;
        if (e < E) atomicAdd(&hist[dst[e] >> 7], 1);
    }
    __syncthreads();
    for (int i = threadIdx.x; i < NBMAX; i += 256) {
        int h = hist[i];
        if (h) atomicAdd(&bcnt[i], h);
    }
}

__global__ __launch_bounds__(1024) void k_bucket_scan(const int* __restrict__ bcnt, int NB,
                                                      int* __restrict__ boffs, int* __restrict__ gfill,
                                                      int E) {
    __shared__ int sd[1024];
    int tid = threadIdx.x;
    int v = (tid < NB) ? bcnt[tid] : 0;
    sd[tid] = v;
    __syncthreads();
    for (int off = 1; off < 1024; off <<= 1) {
        int t = (tid >= off) ? sd[tid - off] : 0;
        __syncthreads();
        sd[tid] += t;
        __syncthreads();
    }
    int excl = sd[tid] - v;
    if (tid < NB) { boffs[tid] = excl; gfill[tid] = excl; }
    if (tid == 0) boffs[NB] = E;
}

__global__ __launch_bounds__(256) void k_bucket_scatter(const int* __restrict__ src,
                                                        const int* __restrict__ dst, int E,
                                                        int* __restrict__ gfill,
                                                        uint32* __restrict__ pairs) {
    __shared__ int hist[NBMAX];
    __shared__ int basea[NBMAX];
    for (int i = threadIdx.x; i < NBMAX; i += 256) hist[i] = 0;
    __syncthreads();
    int base = blockIdx.x * EPB;
    #pragma unroll 4
    for (int i = 0; i < EPB / 256; ++i) {
        int e = base + i * 256 + threadIdx.x;
        if (e < E) atomicAdd(&hist[dst[e] >> 7], 1);
    }
    __syncthreads();
    for (int i = threadIdx.x; i < NBMAX; i += 256) {
        int h = hist[i];
        basea[i] = h ? atomicAdd(&gfill[i], h) : 0;
        hist[i] = 0;   // reuse as per-bucket fill
    }
    __syncthreads();
    #pragma unroll 4
    for (int i = 0; i < EPB / 256; ++i) {
        int e = base + i * 256 + threadIdx.x;
        if (e < E) {
            int d = dst[e];
            int b = d >> 7;
            int pos = basea[b] + atomicAdd(&hist[b], 1);
            pairs[pos] = ((uint32)src[e] << 7) | (uint32)(d & 127);
        }
    }
}

__global__ __launch_bounds__(256) void k_bucket_sort(const uint32* __restrict__ pairs,
                                                     const int* __restrict__ boffs,
                                                     int N, int E,
                                                     int* __restrict__ row_start,
                                                     float* __restrict__ deg_inv,
                                                     int* __restrict__ src_sorted) {
    __shared__ int cnt[128];
    __shared__ int sc[128];
    __shared__ int fill[128];
    int b = blockIdx.x, tid = threadIdx.x;
    int s0 = boffs[b], s1 = boffs[b + 1];
    if (tid < 128) cnt[tid] = 0;
    __syncthreads();
    for (int e = s0 + tid; e < s1; e += 256)
        atomicAdd(&cnt[pairs[e] & 127], 1);
    __syncthreads();
    if (tid < 128) sc[tid] = cnt[tid];
    __syncthreads();
    for (int off = 1; off < 128; off <<= 1) {
        int v = 0;
        if (tid < 128 && tid >= off) v = sc[tid - off];
        __syncthreads();
        if (tid < 128) sc[tid] += v;
        __syncthreads();
    }
    if (tid < 128) {
        int excl = sc[tid] - cnt[tid];
        int node = b * 128 + tid;
        if (node < N) {
            row_start[node] = s0 + excl;
            int d = cnt[tid];
            deg_inv[node] = 1.0f / (float)(d > 1 ? d : 1);
        }
        fill[tid] = s0 + excl;
    }
    if (b == 0 && tid == 0) row_start[N] = E;
    __syncthreads();
    for (int e = s0 + tid; e < s1; e += 256) {
        uint32 p = pairs[e];
        int pos = atomicAdd(&fill[p & 127], 1);
        src_sorted[pos] = (int)(p >> 7);
    }
}

// transpose+cast weights: Wt[c][k] = (c<halfC ? Ws[k][c] : Wn[k][c-halfC]), row-major [2*halfC][K]
__global__ __launch_bounds__(256) void k_wt(const float* __restrict__ Ws, const float* __restrict__ Wn,
                                            int K, int logK, int halfC, unsigned short* __restrict__ Wt) {
    int t = blockIdx.x * blockDim.x + threadIdx.x;
    int total = 2 * halfC * K;
    if (t >= total) return;
    int c = t >> logK, k = t & (K - 1);
    float v = (c < halfC) ? Ws[(size_t)k * halfC + c] : Wn[(size_t)k * halfC + (c - halfC)];
    Wt[t] = f2bf(v);
}

// ---------------- register-streaming MFMA GEMM, fragment-ordered B in LDS ----------------
// D[rows x NF*16 cols] = A[rows x K] @ Wtblk^T.
// Bs layout: fragment f = s*NF + n occupies 1KB; lane l's 16B at f*1024 + l*16
// -> every ds_read_b128 is lane-consecutive (conflict-free, immediate offsets).
// YSPLIT=true (L1, NF=4): blockIdx.y in 0..3 -> 64-col block; y<2 -> bf16 S16,
//   y>=2 -> fp8 N8, both ld 128, col offset (y&1)*64.
// YSPLIT=false (L2, NF=8): frags n<4 -> bf16 S16 (ld 64); n>=4 -> fp8 N8 (ld 64).
// AF32: A is f32, cast to bf16 in regs (convert frees staging regs, then
// prefetch next strip into same regs before MFMA phase).
template<int K, int NF, bool AF32, bool YSPLIT>
__global__ __launch_bounds__(256) void gemm_rs(const void* __restrict__ Aptr, int Arows, int nstrip,
                                               const unsigned short* __restrict__ Wt,
                                               unsigned short* __restrict__ S16,
                                               unsigned char* __restrict__ N8) {
    constexpr int KS = K / 32;                     // K-steps of 32
    __shared__ unsigned short Bs[NF * KS * 512];   // 32 KB for both configs
    const int tid = threadIdx.x;
    const int wave = tid >> 6, lane = tid & 63;
    const int l15 = lane & 15, l4 = lane >> 4;

    const int ycol = YSPLIT ? blockIdx.y * 64 : 0;
    const unsigned short* Wtblk = Wt + (size_t)ycol * K;
    const bool out8 = YSPLIT && (blockIdx.y >= 2);
    const int ybase = YSPLIT ? (blockIdx.y & 1) * 64 : 0;

    // stage B into LDS in fragment order
    for (int i = tid; i < NF * KS * 64; i += 256) {
        int f = i >> 6, l = i & 63;
        int s = f / NF, n = f - s * NF;
        int col = n * 16 + (l & 15);
        int k = s * 32 + (l >> 4) * 8;
        uint4 v = *reinterpret_cast<const uint4*>(&Wtblk[(size_t)col * K + k]);
        *reinterpret_cast<uint4*>(&Bs[(size_t)i * 8]) = v;
    }
    __syncthreads();

    const unsigned short* Bl = Bs + (size_t)lane * 8;   // per-lane base, imm offsets below
    const int stride = gridDim.x;
    int g = blockIdx.x;
    if (g >= nstrip) return;

    float4 a[AF32 ? 2 * KS : 1];   // f32 staging regs
    uint4  ub[AF32 ? 1 : KS];      // bf16 staging regs

    auto loadA = [&](int gg) {
        int arow = gg * 64 + wave * 16 + l15;
        if constexpr (AF32) {
            int r = arow < Arows ? arow : Arows - 1;    // clamp (dup row; pad rows never read)
            const float* Ar = (const float*)Aptr + (size_t)r * K + l4 * 8;
            #pragma unroll
            for (int s = 0; s < KS; ++s) {
                a[2 * s]     = *reinterpret_cast<const float4*>(Ar + s * 32);
                a[2 * s + 1] = *reinterpret_cast<const float4*>(Ar + s * 32 + 4);
            }
        } else {
            const unsigned short* Ar = (const unsigned short*)Aptr + (size_t)arow * K + l4 * 8;
            #pragma unroll
            for (int s = 0; s < KS; ++s)
                ub[s] = *reinterpret_cast<const uint4*>(Ar + s * 32);
        }
    };

    loadA(g);
    while (true) {
        short8 af[KS];
        if constexpr (AF32) {
            #pragma unroll
            for (int s = 0; s < KS; ++s) {      // convert frees a[] for prefetch
                union { uint32 u[4]; short8 v; } cv;
                cv.u[0] = pack2bf(a[2*s].x,   a[2*s].y);
                cv.u[1] = pack2bf(a[2*s].z,   a[2*s].w);
                cv.u[2] = pack2bf(a[2*s+1].x, a[2*s+1].y);
                cv.u[3] = pack2bf(a[2*s+1].z, a[2*s+1].w);
                af[s] = cv.v;
            }
        } else {
            #pragma unroll
            for (int s = 0; s < KS; ++s) {      // reg copy frees ub[]
                union { uint4 q; short8 v; } cv;
                cv.q = ub[s];
                af[s] = cv.v;
            }
        }
        int gn = g + stride;
        if (gn < nstrip) loadA(gn);             // prefetch hides under MFMA+stores

        f32x4 acc[NF] = {};
        #pragma unroll
        for (int s = 0; s < KS; ++s) {
            #pragma unroll
            for (int n = 0; n < NF; ++n) {
                short8 bf = *reinterpret_cast<const short8*>(Bl + (size_t)(s * NF + n) * 512);
                acc[n] = __builtin_amdgcn_mfma_f32_16x16x32_bf16(af[s], bf, acc[n], 0, 0, 0);
            }
        }
        const int rbase = g * 64 + wave * 16;
        #pragma unroll
        for (int n = 0; n < NF; ++n) {
            #pragma unroll
            for (int r = 0; r < 4; ++r) {
                int rw = rbase + l4 * 4 + r;
                if constexpr (YSPLIT) {
                    int col = ybase + n * 16 + l15;
                    if (out8) N8[(size_t)rw * 128 + col] = enc8(acc[n][r]);
                    else      S16[(size_t)rw * 128 + col] = f2bf(acc[n][r]);
                } else {
                    if (n < 4) S16[(size_t)rw * 64 + n * 16 + l15] = f2bf(acc[n][r]);
                    else       N8[(size_t)rw * 64 + (n - 4) * 16 + l15] = enc8(acc[n][r]);
                }
            }
        }
        if (gn >= nstrip) break;
        g = gn;
    }
}

// ---------------- layer-1 aggregate + combine + relu -> h (bf16) ----------------
// one wave/node; 16 lanes per row (uint2 = 8 fp8 cols); 16 edges/iter, 4 gathers in flight.
__global__ __launch_bounds__(256) void k_agg1(const uint2* __restrict__ t1n, const uint4* __restrict__ t1s,
                                              const int* __restrict__ rs, const int* __restrict__ ss,
                                              const float* __restrict__ dinv, const float* __restrict__ b1,
                                              uint4* __restrict__ h, int N) {
    int wid  = (blockIdx.x * blockDim.x + threadIdx.x) >> 6;
    int lane = threadIdx.x & 63;
    if (wid >= N) return;
    int e0 = rs[wid], e1 = rs[wid + 1];
    const int q = lane >> 4, c = lane & 15;
    float a0 = 0, a1 = 0, a2 = 0, a3 = 0, a4 = 0, a5 = 0, a6 = 0, a7 = 0;
    float f0, f1, f2, f3;
    int e = e0;
    for (; e + 16 <= e1; e += 16) {
        int s0 = ss[e + q];
        int s1 = ss[e + 4 + q];
        int s2 = ss[e + 8 + q];
        int s3 = ss[e + 12 + q];
        uint2 v0 = t1n[(size_t)s0 * 16 + c];
        uint2 v1 = t1n[(size_t)s1 * 16 + c];
        uint2 v2 = t1n[(size_t)s2 * 16 + c];
        uint2 v3 = t1n[(size_t)s3 * 16 + c];
        dec_u32(v0.x, f0, f1, f2, f3); a0 += f0; a1 += f1; a2 += f2; a3 += f3;
        dec_u32(v0.y, f0, f1, f2, f3); a4 += f0; a5 += f1; a6 += f2; a7 += f3;
        dec_u32(v1.x, f0, f1, f2, f3); a0 += f0; a1 += f1; a2 += f2; a3 += f3;
        dec_u32(v1.y, f0, f1, f2, f3); a4 += f0; a5 += f1; a6 += f2; a7 += f3;
        dec_u32(v2.x, f0, f1, f2, f3); a0 += f0; a1 += f1; a2 += f2; a3 += f3;
        dec_u32(v2.y, f0, f1, f2, f3); a4 += f0; a5 += f1; a6 += f2; a7 += f3;
        dec_u32(v3.x, f0, f1, f2, f3); a0 += f0; a1 += f1; a2 += f2; a3 += f3;
        dec_u32(v3.y, f0, f1, f2, f3); a4 += f0; a5 += f1; a6 += f2; a7 += f3;
    }
    for (; e < e1; e += 4) {
        if (e + q < e1) {
            int s = ss[e + q];
            uint2 v = t1n[(size_t)s * 16 + c];
            dec_u32(v.x, f0, f1, f2, f3); a0 += f0; a1 += f1; a2 += f2; a3 += f3;
            dec_u32(v.y, f0, f1, f2, f3); a4 += f0; a5 += f1; a6 += f2; a7 += f3;
        }
    }
    a0 += __shfl_xor(a0, 16); a1 += __shfl_xor(a1, 16); a2 += __shfl_xor(a2, 16); a3 += __shfl_xor(a3, 16);
    a4 += __shfl_xor(a4, 16); a5 += __shfl_xor(a5, 16); a6 += __shfl_xor(a6, 16); a7 += __shfl_xor(a7, 16);
    a0 += __shfl_xor(a0, 32); a1 += __shfl_xor(a1, 32); a2 += __shfl_xor(a2, 32); a3 += __shfl_xor(a3, 32);
    a4 += __shfl_xor(a4, 32); a5 += __shfl_xor(a5, 32); a6 += __shfl_xor(a6, 32); a7 += __shfl_xor(a7, 32);
    if (lane < 16) {
        float di = dinv[wid];
        uint4 sv = t1s[(size_t)wid * 16 + c];
        float4 bA = *reinterpret_cast<const float4*>(&b1[c * 8]);
        float4 bB = *reinterpret_cast<const float4*>(&b1[c * 8 + 4]);
        float h0 = fmaxf(fmaf(a0, di, bf_lo(sv.x)) + bA.x, 0.f);
        float h1 = fmaxf(fmaf(a1, di, bf_hi(sv.x)) + bA.y, 0.f);
        float h2 = fmaxf(fmaf(a2, di, bf_lo(sv.y)) + bA.z, 0.f);
        float h3 = fmaxf(fmaf(a3, di, bf_hi(sv.y)) + bA.w, 0.f);
        float h4 = fmaxf(fmaf(a4, di, bf_lo(sv.z)) + bB.x, 0.f);
        float h5 = fmaxf(fmaf(a5, di, bf_hi(sv.z)) + bB.y, 0.f);
        float h6 = fmaxf(fmaf(a6, di, bf_lo(sv.w)) + bB.z, 0.f);
        float h7 = fmaxf(fmaf(a7, di, bf_hi(sv.w)) + bB.w, 0.f);
        uint4 o;
        o.x = pack2bf(h0, h1); o.y = pack2bf(h2, h3);
        o.z = pack2bf(h4, h5); o.w = pack2bf(h6, h7);
        h[(size_t)wid * 16 + c] = o;
    }
}

// ---------------- layer-2 aggregate + combine -> out (f32) ----------------
// one wave/node; 8 lanes per row (uint2 = 8 fp8 cols); 32 edges/iter, 4 gathers in flight.
__global__ __launch_bounds__(256) void k_agg2(const uint2* __restrict__ t2n, const uint4* __restrict__ t2s,
                                              const int* __restrict__ rs, const int* __restrict__ ss,
                                              const float* __restrict__ dinv, const float* __restrict__ b2,
                                              float* __restrict__ out, int N) {
    int wid  = (blockIdx.x * blockDim.x + threadIdx.x) >> 6;
    int lane = threadIdx.x & 63;
    if (wid >= N) return;
    int e0 = rs[wid], e1 = rs[wid + 1];
    const int o8 = lane >> 3, c = lane & 7;
    float a0 = 0, a1 = 0, a2 = 0, a3 = 0, a4 = 0, a5 = 0, a6 = 0, a7 = 0;
    float f0, f1, f2, f3;
    int e = e0;
    for (; e + 32 <= e1; e += 32) {
        int s0 = ss[e + o8];
        int s1 = ss[e + 8 + o8];
        int s2 = ss[e + 16 + o8];
        int s3 = ss[e + 24 + o8];
        uint2 v0 = t2n[(size_t)s0 * 8 + c];
        uint2 v1 = t2n[(size_t)s1 * 8 + c];
        uint2 v2 = t2n[(size_t)s2 * 8 + c];
        uint2 v3 = t2n[(size_t)s3 * 8 + c];
        dec_u32(v0.x, f0, f1, f2, f3); a0 += f0; a1 += f1; a2 += f2; a3 += f3;
        dec_u32(v0.y, f0, f1, f2, f3); a4 += f0; a5 += f1; a6 += f2; a7 += f3;
        dec_u32(v1.x, f0, f1, f2, f3); a0 += f0; a1 += f1; a2 += f2; a3 += f3;
        dec_u32(v1.y, f0, f1, f2, f3); a4 += f0; a5 += f1; a6 += f2; a7 += f3;
        dec_u32(v2.x, f0, f1, f2, f3); a0 += f0; a1 += f1; a2 += f2; a3 += f3;
        dec_u32(v2.y, f0, f1, f2, f3); a4 += f0; a5 += f1; a6 += f2; a7 += f3;
        dec_u32(v3.x, f0, f1, f2, f3); a0 += f0; a1 += f1; a2 += f2; a3 += f3;
        dec_u32(v3.y, f0, f1, f2, f3); a4 += f0; a5 += f1; a6 += f2; a7 += f3;
    }
    for (; e < e1; e += 8) {
        if (e + o8 < e1) {
            int s = ss[e + o8];
            uint2 v = t2n[(size_t)s * 8 + c];
            dec_u32(v.x, f0, f1, f2, f3); a0 += f0; a1 += f1; a2 += f2; a3 += f3;
            dec_u32(v.y, f0, f1, f2, f3); a4 += f0; a5 += f1; a6 += f2; a7 += f3;
        }
    }
    a0 += __shfl_xor(a0, 8);  a1 += __shfl_xor(a1, 8);  a2 += __shfl_xor(a2, 8);  a3 += __shfl_xor(a3, 8);
    a4 += __shfl_xor(a4, 8);  a5 += __shfl_xor(a5, 8);  a6 += __shfl_xor(a6, 8);  a7 += __shfl_xor(a7, 8);
    a0 += __shfl_xor(a0, 16); a1 += __shfl_xor(a1, 16); a2 += __shfl_xor(a2, 16); a3 += __shfl_xor(a3, 16);
    a4 += __shfl_xor(a4, 16); a5 += __shfl_xor(a5, 16); a6 += __shfl_xor(a6, 16); a7 += __shfl_xor(a7, 16);
    a0 += __shfl_xor(a0, 32); a1 += __shfl_xor(a1, 32); a2 += __shfl_xor(a2, 32); a3 += __shfl_xor(a3, 32);
    a4 += __shfl_xor(a4, 32); a5 += __shfl_xor(a5, 32); a6 += __shfl_xor(a6, 32); a7 += __shfl_xor(a7, 32);
    if (lane < 8) {
        float di = dinv[wid];
        uint4 sv = t2s[(size_t)wid * 8 + c];
        float4 bA = *reinterpret_cast<const float4*>(&b2[c * 8]);
        float4 bB = *reinterpret_cast<const float4*>(&b2[c * 8 + 4]);
        float4 oA, oB;
        oA.x = fmaf(a0, di, bf_lo(sv.x)) + bA.x;
        oA.y = fmaf(a1, di, bf_hi(sv.x)) + bA.y;
        oA.z = fmaf(a2, di, bf_lo(sv.y)) + bA.z;
        oA.w = fmaf(a3, di, bf_hi(sv.y)) + bA.w;
        oB.x = fmaf(a4, di, bf_lo(sv.z)) + bB.x;
        oB.y = fmaf(a5, di, bf_hi(sv.z)) + bB.y;
        oB.z = fmaf(a6, di, bf_lo(sv.w)) + bB.z;
        oB.w = fmaf(a7, di, bf_hi(sv.w)) + bB.w;
        *reinterpret_cast<float4*>(&out[(size_t)wid * 64 + c * 8]) = oA;
        *reinterpret_cast<float4*>(&out[(size_t)wid * 64 + c * 8 + 4]) = oB;
    }
}

extern "C" void kernel_launch(void* const* d_in, const int* in_sizes, int n_in,
                              void* d_out, int out_size, void* d_ws, size_t ws_size,
                              hipStream_t stream) {
    const float* x   = (const float*)d_in[0];
    const int*   src = (const int*)d_in[1];
    const int*   dst = (const int*)d_in[2];
    const float* W1s = (const float*)d_in[3];
    const float* W1n = (const float*)d_in[4];
    const float* b1  = (const float*)d_in[5];
    const float* W2s = (const float*)d_in[6];
    const float* W2n = (const float*)d_in[7];
    const float* b2  = (const float*)d_in[8];
    float* out = (float*)d_out;

    const int IN = 256, H = 128, OUT = 64;
    const int N  = in_sizes[0] / IN;
    const int E  = in_sizes[1];
    const int Mpad = (N + 127) & ~127;
    const int NB = (N + 127) >> 7;

    char* ws = (char*)d_ws;
    size_t off = 0;
    auto alloc = [&](size_t bytes) -> char* {
        char* p = ws + off;
        off = (off + bytes + 255) & ~(size_t)255;
        return p;
    };
    int*   row_start  = (int*)  alloc((size_t)(N + 1) * 4);
    float* deg_inv    = (float*)alloc((size_t)N * 4);
    int*   bcnt       = (int*)  alloc((size_t)NBMAX * 4);
    int*   boffs      = (int*)  alloc((size_t)(NBMAX + 1) * 4);
    int*   gfill      = (int*)  alloc((size_t)NBMAX * 4);
    int*   src_sorted = (int*)  alloc((size_t)E * 4);
    uint32* pairs     = (uint32*)alloc((size_t)E * 4);
    unsigned short* Wt1 = (unsigned short*)alloc((size_t)(2 * H) * IN * 2);
    unsigned short* Wt2 = (unsigned short*)alloc((size_t)(2 * OUT) * H * 2);
    unsigned short* t1s = (unsigned short*)alloc((size_t)Mpad * H * 2);  // bf16 self; reused as t2s (ld 64)
    unsigned char*  t1n = (unsigned char*) alloc((size_t)Mpad * H);     // fp8 neigh; reused as t2n (ld 64)
    unsigned short* hbf = (unsigned short*)alloc((size_t)Mpad * H * 2); // layer-1 output (bf16)

    // 1. CSR build via two-level bucket sort
    hipMemsetAsync(bcnt, 0, (size_t)NBMAX * 4, stream);
    int nblk = (E + EPB - 1) / EPB;
    k_bucket_count  <<<nblk, 256, 0, stream>>>(dst, E, bcnt);
    k_bucket_scan   <<<1, 1024, 0, stream>>>(bcnt, NB, boffs, gfill, E);
    k_bucket_scatter<<<nblk, 256, 0, stream>>>(src, dst, E, gfill, pairs);
    k_bucket_sort   <<<NB, 256, 0, stream>>>(pairs, boffs, N, E, row_start, deg_inv, src_sorted);

    // 2. weight transpose+cast
    k_wt<<<(2 * H * IN + 255) / 256, 256, 0, stream>>>(W1s, W1n, IN, 8, H, Wt1);
    k_wt<<<(2 * OUT * H + 255) / 256, 256, 0, stream>>>(W2s, W2n, H, 7, OUT, Wt2);

    // 3. layer 1 GEMM (fused f32->bf16 cast): x -> t1s bf16 [Mpad x 128], t1n fp8 [Mpad x 128]
    int nstrip1 = (N + 63) / 64;
    gemm_rs<256, 4, true, true><<<dim3(512, 4), 256, 0, stream>>>(x, N, nstrip1, Wt1, t1s, t1n);
    // 4. aggregate + relu -> h bf16
    k_agg1<<<(N + 3) / 4, 256, 0, stream>>>((const uint2*)t1n, (const uint4*)t1s,
                                            row_start, src_sorted, deg_inv, b1, (uint4*)hbf, N);
    // 5. layer 2 GEMM: hbf -> t2s bf16 [Mpad x 64] + t2n fp8 [Mpad x 64] (reuse t1s/t1n)
    int nstrip2 = Mpad / 64;
    gemm_rs<128, 8, false, false><<<dim3(512, 1), 256, 0, stream>>>(hbf, Mpad, nstrip2, Wt2, t1s, t1n);
    // 6. aggregate -> out f32
    k_agg2<<<(N + 3) / 4, 256, 0, stream>>>((const uint2*)t1n, (const uint4*)t1s,
                                            row_start, src_sorted, deg_inv, b2, out, N);
}

// Round 9
// 322.455 us; speedup vs baseline: 1.0815x; 1.0815x over previous
//
#include <hip/hip_runtime.h>
#include <hip/hip_bf16.h>

// GraphSAGE 2-layer: bucket-sort CSR build + bf16 MFMA transform-then-aggregate.
// N=100000, E=3.2M, IN=256, H=128, OUT=64.
// x pre-cast to bf16 (streaming). GEMM: B resident in LDS in fragment order
// (conflict-free), 512 threads / 8 waves, register double-buffer across strips.
// Neighbor buffers (t1n/t2n) stored fp8-e4m3 (halved gather traffic).

typedef unsigned int uint32;
typedef __attribute__((ext_vector_type(8))) short short8;
typedef __attribute__((ext_vector_type(4))) float f32x4;

#define NBMAX 1024     // max buckets (N <= 131072 at 128 nodes/bucket)
#define EPB   8192     // edges per block in bucket count/scatter

#if defined(__has_builtin)
#if __has_builtin(__builtin_amdgcn_cvt_pk_f32_fp8) && __has_builtin(__builtin_amdgcn_cvt_pk_fp8_f32)
#define FP8_HW 1
#endif
#endif
#ifndef FP8_HW
#define FP8_HW 0
#endif

__device__ __forceinline__ unsigned short f2bf(float f) {
    unsigned u = __float_as_uint(f);
    u += 0x7fffu + ((u >> 16) & 1u);      // RNE
    return (unsigned short)(u >> 16);
}
__device__ __forceinline__ uint32 pack2bf(float lo, float hi) {
    return (uint32)f2bf(lo) | ((uint32)f2bf(hi) << 16);
}
__device__ __forceinline__ float bf_lo(uint32 v) { return __uint_as_float(v << 16); }
__device__ __forceinline__ float bf_hi(uint32 v) { return __uint_as_float(v & 0xFFFF0000u); }

// ---- fp8 e4m3 encode/decode ----
__device__ __forceinline__ unsigned char enc8(float v) {
#if FP8_HW
    return (unsigned char)(__builtin_amdgcn_cvt_pk_fp8_f32(v, v, 0, false) & 0xFF);
#else
    float g = v * 0x1p-120f;
    uint32 b = __float_as_uint(g);
    uint32 s = (b >> 24) & 0x80u;
    b &= 0x7fffffffu;
    b += 0x7ffffu + ((b >> 20) & 1u);     // RNE to 3 mantissa bits
    int t = (int)(b >> 20) - 960;
    t = t < 0 ? 0 : (t > 126 ? 126 : t);
    return (unsigned char)(s | (uint32)t);
#endif
}
#if !FP8_HW
__device__ __forceinline__ float dec1(uint32 b) {
    uint32 bits = ((b & 0x80u) << 24) | ((b & 0x7fu) << 20);
    return __uint_as_float(bits) * 0x1p+120f;
}
#endif
__device__ __forceinline__ void dec_u32(uint32 u, float& f0, float& f1, float& f2, float& f3) {
#if FP8_HW
    auto lo = __builtin_amdgcn_cvt_pk_f32_fp8(u, false);
    auto hi = __builtin_amdgcn_cvt_pk_f32_fp8(u, true);
    f0 = lo[0]; f1 = lo[1]; f2 = hi[0]; f3 = hi[1];
#else
    f0 = dec1(u & 0xffu); f1 = dec1((u >> 8) & 0xffu);
    f2 = dec1((u >> 16) & 0xffu); f3 = dec1(u >> 24);
#endif
}

// ---------------- bucket-sort CSR build (bucket = dst >> 7) ----------------
__global__ __launch_bounds__(256) void k_bucket_count(const int* __restrict__ dst, int E,
                                                      int* __restrict__ bcnt) {
    __shared__ int hist[NBMAX];
    for (int i = threadIdx.x; i < NBMAX; i += 256) hist[i] = 0;
    __syncthreads();
    int base = blockIdx.x * EPB;
    #pragma unroll 4
    for (int i = 0; i < EPB / 256; ++i) {
        int e = base + i * 256 + threadIdx.x;
        if (e < E) atomicAdd(&hist[dst[e] >> 7], 1);
    }
    __syncthreads();
    for (int i = threadIdx.x; i < NBMAX; i += 256) {
        int h = hist[i];
        if (h) atomicAdd(&bcnt[i], h);
    }
}

__global__ __launch_bounds__(1024) void k_bucket_scan(const int* __restrict__ bcnt, int NB,
                                                      int* __restrict__ boffs, int* __restrict__ gfill,
                                                      int E) {
    __shared__ int sd[1024];
    int tid = threadIdx.x;
    int v = (tid < NB) ? bcnt[tid] : 0;
    sd[tid] = v;
    __syncthreads();
    for (int off = 1; off < 1024; off <<= 1) {
        int t = (tid >= off) ? sd[tid - off] : 0;
        __syncthreads();
        sd[tid] += t;
        __syncthreads();
    }
    int excl = sd[tid] - v;
    if (tid < NB) { boffs[tid] = excl; gfill[tid] = excl; }
    if (tid == 0) boffs[NB] = E;
}

__global__ __launch_bounds__(256) void k_bucket_scatter(const int* __restrict__ src,
                                                        const int* __restrict__ dst, int E,
                                                        int* __restrict__ gfill,
                                                        uint32* __restrict__ pairs) {
    __shared__ int hist[NBMAX];
    __shared__ int basea[NBMAX];
    for (int i = threadIdx.x; i < NBMAX; i += 256) hist[i] = 0;
    __syncthreads();
    int base = blockIdx.x * EPB;
    #pragma unroll 4
    for (int i = 0; i < EPB / 256; ++i) {
        int e = base + i * 256 + threadIdx.x;
        if (e < E) atomicAdd(&hist[dst[e] >> 7], 1);
    }
    __syncthreads();
    for (int i = threadIdx.x; i < NBMAX; i += 256) {
        int h = hist[i];
        basea[i] = h ? atomicAdd(&gfill[i], h) : 0;
        hist[i] = 0;   // reuse as per-bucket fill
    }
    __syncthreads();
    #pragma unroll 4
    for (int i = 0; i < EPB / 256; ++i) {
        int e = base + i * 256 + threadIdx.x;
        if (e < E) {
            int d = dst[e];
            int b = d >> 7;
            int pos = basea[b] + atomicAdd(&hist[b], 1);
            pairs[pos] = ((uint32)src[e] << 7) | (uint32)(d & 127);
        }
    }
}

__global__ __launch_bounds__(256) void k_bucket_sort(const uint32* __restrict__ pairs,
                                                     const int* __restrict__ boffs,
                                                     int N, int E,
                                                     int* __restrict__ row_start,
                                                     float* __restrict__ deg_inv,
                                                     int* __restrict__ src_sorted) {
    __shared__ int cnt[128];
    __shared__ int sc[128];
    __shared__ int fill[128];
    int b = blockIdx.x, tid = threadIdx.x;
    int s0 = boffs[b], s1 = boffs[b + 1];
    if (tid < 128) cnt[tid] = 0;
    __syncthreads();
    for (int e = s0 + tid; e < s1; e += 256)
        atomicAdd(&cnt[pairs[e] & 127], 1);
    __syncthreads();
    if (tid < 128) sc[tid] = cnt[tid];
    __syncthreads();
    for (int off = 1; off < 128; off <<= 1) {
        int v = 0;
        if (tid < 128 && tid >= off) v = sc[tid - off];
        __syncthreads();
        if (tid < 128) sc[tid] += v;
        __syncthreads();
    }
    if (tid < 128) {
        int excl = sc[tid] - cnt[tid];
        int node = b * 128 + tid;
        if (node < N) {
            row_start[node] = s0 + excl;
            int d = cnt[tid];
            deg_inv[node] = 1.0f / (float)(d > 1 ? d : 1);
        }
        fill[tid] = s0 + excl;
    }
    if (b == 0 && tid == 0) row_start[N] = E;
    __syncthreads();
    for (int e = s0 + tid; e < s1; e += 256) {
        uint32 p = pairs[e];
        int pos = atomicAdd(&fill[p & 127], 1);
        src_sorted[pos] = (int)(p >> 7);
    }
}

// ---------------- x f32 -> bf16 pre-cast (zero-fills pad rows) ----------------
__global__ __launch_bounds__(256) void k_cast_x(const float* __restrict__ x, uint32* __restrict__ xb,
                                                long n8, long total8) {
    long t = (long)blockIdx.x * blockDim.x + threadIdx.x;
    if (t >= total8) return;
    uint4 o = make_uint4(0u, 0u, 0u, 0u);
    if (t < n8) {
        const float4* p = reinterpret_cast<const float4*>(x) + t * 2;
        float4 a = p[0], b = p[1];
        o.x = pack2bf(a.x, a.y); o.y = pack2bf(a.z, a.w);
        o.z = pack2bf(b.x, b.y); o.w = pack2bf(b.z, b.w);
    }
    reinterpret_cast<uint4*>(xb)[t] = o;
}

// transpose+cast weights: Wt[c][k] = (c<halfC ? Ws[k][c] : Wn[k][c-halfC]), row-major [2*halfC][K]
__global__ __launch_bounds__(256) void k_wt(const float* __restrict__ Ws, const float* __restrict__ Wn,
                                            int K, int logK, int halfC, unsigned short* __restrict__ Wt) {
    int t = blockIdx.x * blockDim.x + threadIdx.x;
    int total = 2 * halfC * K;
    if (t >= total) return;
    int c = t >> logK, k = t & (K - 1);
    float v = (c < halfC) ? Ws[(size_t)k * halfC + c] : Wn[(size_t)k * halfC + (c - halfC)];
    Wt[t] = f2bf(v);
}

// ---------------- register-streaming MFMA GEMM, fragment-ordered B in LDS ----------------
// D[rows x 128cols] = A[rows x K](bf16) @ Wtblk^T.
// Bs: fragment f = s*NF + n occupies 1KB; lane l's 16B at f*1024 + l*16 ->
// every ds_read_b128 lane-consecutive (conflict-free, immediate offsets).
// 512 threads = 8 waves; strip = 128 rows/block (wave w owns rows w*16..w*16+15).
// Register double-buffer across strips: loads for strip g+1 issued before
// MFMAing strip g.
// YSPLIT=true (L1): blockIdx.y=0 -> bf16 to S16[ld 128]; y=1 -> fp8 to N8[ld 128].
// YSPLIT=false (L2): frags n<4 -> bf16 S16[ld 64]; n>=4 -> fp8 N8[ld 64].
template<int K, int NF, bool YSPLIT>
__global__ __launch_bounds__(512) void gemm_rs(const unsigned short* __restrict__ A, int nstrip,
                                               const unsigned short* __restrict__ Wt,
                                               unsigned short* __restrict__ S16,
                                               unsigned char* __restrict__ N8) {
    constexpr int KS = K / 32;                     // K-steps of 32
    __shared__ unsigned short Bs[NF * KS * 512];   // 64KB (L1) / 32KB (L2)
    const int tid = threadIdx.x;
    const int wave = tid >> 6, lane = tid & 63;
    const int l15 = lane & 15, l4 = lane >> 4;

    const unsigned short* Wtblk = Wt + (YSPLIT ? (size_t)blockIdx.y * 128 * K : 0);
    const bool out8 = YSPLIT && (blockIdx.y == 1);

    // stage B into LDS in fragment order
    for (int i = tid; i < NF * KS * 64; i += 512) {
        int f = i >> 6, l = i & 63;
        int s = f / NF, n = f - s * NF;
        int col = n * 16 + (l & 15);
        int k = s * 32 + (l >> 4) * 8;
        uint4 v = *reinterpret_cast<const uint4*>(&Wtblk[(size_t)col * K + k]);
        *reinterpret_cast<uint4*>(&Bs[(size_t)i * 8]) = v;
    }
    __syncthreads();

    const unsigned short* Bl = Bs + (size_t)lane * 8;   // per-lane base, imm offsets below
    const int stride = gridDim.x;
    int g = blockIdx.x;
    if (g >= nstrip) return;

    uint4 uA[KS], uB[KS];

    auto loadA = [&](int gg, uint4* u) {
        int arow = gg * 128 + wave * 16 + l15;
        const unsigned short* Ar = A + (size_t)arow * K + l4 * 8;
        #pragma unroll
        for (int s = 0; s < KS; ++s)
            u[s] = *reinterpret_cast<const uint4*>(Ar + s * 32);
    };

    auto compute = [&](int gc, uint4* u) {
        f32x4 acc[NF] = {};
        #pragma unroll
        for (int s = 0; s < KS; ++s) {
            union { uint4 q; short8 v; } cv;
            cv.q = u[s];
            short8 af = cv.v;
            #pragma unroll
            for (int n = 0; n < NF; ++n) {
                short8 bf = *reinterpret_cast<const short8*>(Bl + (size_t)(s * NF + n) * 512);
                acc[n] = __builtin_amdgcn_mfma_f32_16x16x32_bf16(af, bf, acc[n], 0, 0, 0);
            }
        }
        const int rbase = gc * 128 + wave * 16;
        #pragma unroll
        for (int n = 0; n < NF; ++n) {
            #pragma unroll
            for (int r = 0; r < 4; ++r) {
                int rw = rbase + l4 * 4 + r;
                if constexpr (YSPLIT) {
                    int col = n * 16 + l15;
                    if (out8) N8[(size_t)rw * 128 + col] = enc8(acc[n][r]);
                    else      S16[(size_t)rw * 128 + col] = f2bf(acc[n][r]);
                } else {
                    if (n < 4) S16[(size_t)rw * 64 + n * 16 + l15] = f2bf(acc[n][r]);
                    else       N8[(size_t)rw * 64 + (n - 4) * 16 + l15] = enc8(acc[n][r]);
                }
            }
        }
    };

    loadA(g, uA);
    while (true) {
        int gn = g + stride;
        if (gn < nstrip) loadA(gn, uB);     // prefetch overlaps entire compute(g)
        compute(g, uA);
        if (gn >= nstrip) break;
        g = gn;
        gn = g + stride;
        if (gn < nstrip) loadA(gn, uA);
        compute(g, uB);
        if (gn >= nstrip) break;
        g = gn;
    }
}

// ---------------- layer-1 aggregate + combine + relu -> h (bf16) ----------------
// one wave/node; 16 lanes per row (uint2 = 8 fp8 cols); 16 edges/iter, 4 gathers in flight.
__global__ __launch_bounds__(256) void k_agg1(const uint2* __restrict__ t1n, const uint4* __restrict__ t1s,
                                              const int* __restrict__ rs, const int* __restrict__ ss,
                                              const float* __restrict__ dinv, const float* __restrict__ b1,
                                              uint4* __restrict__ h, int N) {
    int wid  = (blockIdx.x * blockDim.x + threadIdx.x) >> 6;
    int lane = threadIdx.x & 63;
    if (wid >= N) return;
    int e0 = rs[wid], e1 = rs[wid + 1];
    const int q = lane >> 4, c = lane & 15;
    float a0 = 0, a1 = 0, a2 = 0, a3 = 0, a4 = 0, a5 = 0, a6 = 0, a7 = 0;
    float f0, f1, f2, f3;
    int e = e0;
    for (; e + 16 <= e1; e += 16) {
        int s0 = ss[e + q];
        int s1 = ss[e + 4 + q];
        int s2 = ss[e + 8 + q];
        int s3 = ss[e + 12 + q];
        uint2 v0 = t1n[(size_t)s0 * 16 + c];
        uint2 v1 = t1n[(size_t)s1 * 16 + c];
        uint2 v2 = t1n[(size_t)s2 * 16 + c];
        uint2 v3 = t1n[(size_t)s3 * 16 + c];
        dec_u32(v0.x, f0, f1, f2, f3); a0 += f0; a1 += f1; a2 += f2; a3 += f3;
        dec_u32(v0.y, f0, f1, f2, f3); a4 += f0; a5 += f1; a6 += f2; a7 += f3;
        dec_u32(v1.x, f0, f1, f2, f3); a0 += f0; a1 += f1; a2 += f2; a3 += f3;
        dec_u32(v1.y, f0, f1, f2, f3); a4 += f0; a5 += f1; a6 += f2; a7 += f3;
        dec_u32(v2.x, f0, f1, f2, f3); a0 += f0; a1 += f1; a2 += f2; a3 += f3;
        dec_u32(v2.y, f0, f1, f2, f3); a4 += f0; a5 += f1; a6 += f2; a7 += f3;
        dec_u32(v3.x, f0, f1, f2, f3); a0 += f0; a1 += f1; a2 += f2; a3 += f3;
        dec_u32(v3.y, f0, f1, f2, f3); a4 += f0; a5 += f1; a6 += f2; a7 += f3;
    }
    for (; e < e1; e += 4) {
        if (e + q < e1) {
            int s = ss[e + q];
            uint2 v = t1n[(size_t)s * 16 + c];
            dec_u32(v.x, f0, f1, f2, f3); a0 += f0; a1 += f1; a2 += f2; a3 += f3;
            dec_u32(v.y, f0, f1, f2, f3); a4 += f0; a5 += f1; a6 += f2; a7 += f3;
        }
    }
    a0 += __shfl_xor(a0, 16); a1 += __shfl_xor(a1, 16); a2 += __shfl_xor(a2, 16); a3 += __shfl_xor(a3, 16);
    a4 += __shfl_xor(a4, 16); a5 += __shfl_xor(a5, 16); a6 += __shfl_xor(a6, 16); a7 += __shfl_xor(a7, 16);
    a0 += __shfl_xor(a0, 32); a1 += __shfl_xor(a1, 32); a2 += __shfl_xor(a2, 32); a3 += __shfl_xor(a3, 32);
    a4 += __shfl_xor(a4, 32); a5 += __shfl_xor(a5, 32); a6 += __shfl_xor(a6, 32); a7 += __shfl_xor(a7, 32);
    if (lane < 16) {
        float di = dinv[wid];
        uint4 sv = t1s[(size_t)wid * 16 + c];
        float4 bA = *reinterpret_cast<const float4*>(&b1[c * 8]);
        float4 bB = *reinterpret_cast<const float4*>(&b1[c * 8 + 4]);
        float h0 = fmaxf(fmaf(a0, di, bf_lo(sv.x)) + bA.x, 0.f);
        float h1 = fmaxf(fmaf(a1, di, bf_hi(sv.x)) + bA.y, 0.f);
        float h2 = fmaxf(fmaf(a2, di, bf_lo(sv.y)) + bA.z, 0.f);
        float h3 = fmaxf(fmaf(a3, di, bf_hi(sv.y)) + bA.w, 0.f);
        float h4 = fmaxf(fmaf(a4, di, bf_lo(sv.z)) + bB.x, 0.f);
        float h5 = fmaxf(fmaf(a5, di, bf_hi(sv.z)) + bB.y, 0.f);
        float h6 = fmaxf(fmaf(a6, di, bf_lo(sv.w)) + bB.z, 0.f);
        float h7 = fmaxf(fmaf(a7, di, bf_hi(sv.w)) + bB.w, 0.f);
        uint4 o;
        o.x = pack2bf(h0, h1); o.y = pack2bf(h2, h3);
        o.z = pack2bf(h4, h5); o.w = pack2bf(h6, h7);
        h[(size_t)wid * 16 + c] = o;
    }
}

// ---------------- layer-2 aggregate + combine -> out (f32) ----------------
// one wave/node; 8 lanes per row (uint2 = 8 fp8 cols); 32 edges/iter, 4 gathers in flight.
__global__ __launch_bounds__(256) void k_agg2(const uint2* __restrict__ t2n, const uint4* __restrict__ t2s,
                                              const int* __restrict__ rs, const int* __restrict__ ss,
                                              const float* __restrict__ dinv, const float* __restrict__ b2,
                                              float* __restrict__ out, int N) {
    int wid  = (blockIdx.x * blockDim.x + threadIdx.x) >> 6;
    int lane = threadIdx.x & 63;
    if (wid >= N) return;
    int e0 = rs[wid], e1 = rs[wid + 1];
    const int o8 = lane >> 3, c = lane & 7;
    float a0 = 0, a1 = 0, a2 = 0, a3 = 0, a4 = 0, a5 = 0, a6 = 0, a7 = 0;
    float f0, f1, f2, f3;
    int e = e0;
    for (; e + 32 <= e1; e += 32) {
        int s0 = ss[e + o8];
        int s1 = ss[e + 8 + o8];
        int s2 = ss[e + 16 + o8];
        int s3 = ss[e + 24 + o8];
        uint2 v0 = t2n[(size_t)s0 * 8 + c];
        uint2 v1 = t2n[(size_t)s1 * 8 + c];
        uint2 v2 = t2n[(size_t)s2 * 8 + c];
        uint2 v3 = t2n[(size_t)s3 * 8 + c];
        dec_u32(v0.x, f0, f1, f2, f3); a0 += f0; a1 += f1; a2 += f2; a3 += f3;
        dec_u32(v0.y, f0, f1, f2, f3); a4 += f0; a5 += f1; a6 += f2; a7 += f3;
        dec_u32(v1.x, f0, f1, f2, f3); a0 += f0; a1 += f1; a2 += f2; a3 += f3;
        dec_u32(v1.y, f0, f1, f2, f3); a4 += f0; a5 += f1; a6 += f2; a7 += f3;
        dec_u32(v2.x, f0, f1, f2, f3); a0 += f0; a1 += f1; a2 += f2; a3 += f3;
        dec_u32(v2.y, f0, f1, f2, f3); a4 += f0; a5 += f1; a6 += f2; a7 += f3;
        dec_u32(v3.x, f0, f1, f2, f3); a0 += f0; a1 += f1; a2 += f2; a3 += f3;
        dec_u32(v3.y, f0, f1, f2, f3); a4 += f0; a5 += f1; a6 += f2; a7 += f3;
    }
    for (; e < e1; e += 8) {
        if (e + o8 < e1) {
            int s = ss[e + o8];
            uint2 v = t2n[(size_t)s * 8 + c];
            dec_u32(v.x, f0, f1, f2, f3); a0 += f0; a1 += f1; a2 += f2; a3 += f3;
            dec_u32(v.y, f0, f1, f2, f3); a4 += f0; a5 += f1; a6 += f2; a7 += f3;
        }
    }
    a0 += __shfl_xor(a0, 8);  a1 += __shfl_xor(a1, 8);  a2 += __shfl_xor(a2, 8);  a3 += __shfl_xor(a3, 8);
    a4 += __shfl_xor(a4, 8);  a5 += __shfl_xor(a5, 8);  a6 += __shfl_xor(a6, 8);  a7 += __shfl_xor(a7, 8);
    a0 += __shfl_xor(a0, 16); a1 += __shfl_xor(a1, 16); a2 += __shfl_xor(a2, 16); a3 += __shfl_xor(a3, 16);
    a4 += __shfl_xor(a4, 16); a5 += __shfl_xor(a5, 16); a6 += __shfl_xor(a6, 16); a7 += __shfl_xor(a7, 16);
    a0 += __shfl_xor(a0, 32); a1 += __shfl_xor(a1, 32); a2 += __shfl_xor(a2, 32); a3 += __shfl_xor(a3, 32);
    a4 += __shfl_xor(a4, 32); a5 += __shfl_xor(a5, 32); a6 += __shfl_xor(a6, 32); a7 += __shfl_xor(a7, 32);
    if (lane < 8) {
        float di = dinv[wid];
        uint4 sv = t2s[(size_t)wid * 8 + c];
        float4 bA = *reinterpret_cast<const float4*>(&b2[c * 8]);
        float4 bB = *reinterpret_cast<const float4*>(&b2[c * 8 + 4]);
        float4 oA, oB;
        oA.x = fmaf(a0, di, bf_lo(sv.x)) + bA.x;
        oA.y = fmaf(a1, di, bf_hi(sv.x)) + bA.y;
        oA.z = fmaf(a2, di, bf_lo(sv.y)) + bA.z;
        oA.w = fmaf(a3, di, bf_hi(sv.y)) + bA.w;
        oB.x = fmaf(a4, di, bf_lo(sv.z)) + bB.x;
        oB.y = fmaf(a5, di, bf_hi(sv.z)) + bB.y;
        oB.z = fmaf(a6, di, bf_lo(sv.w)) + bB.z;
        oB.w = fmaf(a7, di, bf_hi(sv.w)) + bB.w;
        *reinterpret_cast<float4*>(&out[(size_t)wid * 64 + c * 8]) = oA;
        *reinterpret_cast<float4*>(&out[(size_t)wid * 64 + c * 8 + 4]) = oB;
    }
}

extern "C" void kernel_launch(void* const* d_in, const int* in_sizes, int n_in,
                              void* d_out, int out_size, void* d_ws, size_t ws_size,
                              hipStream_t stream) {
    const float* x   = (const float*)d_in[0];
    const int*   src = (const int*)d_in[1];
    const int*   dst = (const int*)d_in[2];
    const float* W1s = (const float*)d_in[3];
    const float* W1n = (const float*)d_in[4];
    const float* b1  = (const float*)d_in[5];
    const float* W2s = (const float*)d_in[6];
    const float* W2n = (const float*)d_in[7];
    const float* b2  = (const float*)d_in[8];
    float* out = (float*)d_out;

    const int IN = 256, H = 128, OUT = 64;
    const int N  = in_sizes[0] / IN;
    const int E  = in_sizes[1];
    const int Mpad = (N + 127) & ~127;
    const int NB = (N + 127) >> 7;

    char* ws = (char*)d_ws;
    size_t off = 0;
    auto alloc = [&](size_t bytes) -> char* {
        char* p = ws + off;
        off = (off + bytes + 255) & ~(size_t)255;
        return p;
    };
    int*   row_start  = (int*)  alloc((size_t)(N + 1) * 4);
    float* deg_inv    = (float*)alloc((size_t)N * 4);
    int*   bcnt       = (int*)  alloc((size_t)NBMAX * 4);
    int*   boffs      = (int*)  alloc((size_t)(NBMAX + 1) * 4);
    int*   gfill      = (int*)  alloc((size_t)NBMAX * 4);
    int*   src_sorted = (int*)  alloc((size_t)E * 4);
    uint32* pairs     = (uint32*)alloc((size_t)E * 4);
    unsigned short* xb  = (unsigned short*)alloc((size_t)Mpad * IN * 2);  // bf16 x (pad rows zero)
    unsigned short* Wt1 = (unsigned short*)alloc((size_t)(2 * H) * IN * 2);
    unsigned short* Wt2 = (unsigned short*)alloc((size_t)(2 * OUT) * H * 2);
    unsigned short* t1s = (unsigned short*)alloc((size_t)Mpad * H * 2);  // bf16 self; reused as t2s (ld 64)
    unsigned char*  t1n = (unsigned char*) alloc((size_t)Mpad * H);     // fp8 neigh; reused as t2n (ld 64)
    unsigned short* hbf = (unsigned short*)alloc((size_t)Mpad * H * 2); // layer-1 output (bf16)

    // 1. CSR build via two-level bucket sort
    hipMemsetAsync(bcnt, 0, (size_t)NBMAX * 4, stream);
    int nblk = (E + EPB - 1) / EPB;
    k_bucket_count  <<<nblk, 256, 0, stream>>>(dst, E, bcnt);
    k_bucket_scan   <<<1, 1024, 0, stream>>>(bcnt, NB, boffs, gfill, E);
    k_bucket_scatter<<<nblk, 256, 0, stream>>>(src, dst, E, gfill, pairs);
    k_bucket_sort   <<<NB, 256, 0, stream>>>(pairs, boffs, N, E, row_start, deg_inv, src_sorted);

    // 2. casts: x -> bf16 (pad rows zero), weights transpose+cast
    long n8 = (long)N * IN / 8, total8 = (long)Mpad * IN / 8;
    k_cast_x<<<(int)((total8 + 255) / 256), 256, 0, stream>>>(x, (uint32*)xb, n8, total8);
    k_wt<<<(2 * H * IN + 255) / 256, 256, 0, stream>>>(W1s, W1n, IN, 8, H, Wt1);
    k_wt<<<(2 * OUT * H + 255) / 256, 256, 0, stream>>>(W2s, W2n, H, 7, OUT, Wt2);

    // 3. layer 1 GEMM: xb -> t1s bf16 [Mpad x 128] (y=0), t1n fp8 [Mpad x 128] (y=1)
    int nstrip1 = Mpad / 128;
    gemm_rs<256, 8, true><<<dim3(256, 2), 512, 0, stream>>>(xb, nstrip1, Wt1, t1s, t1n);
    // 4. aggregate + relu -> h bf16
    k_agg1<<<(N + 3) / 4, 256, 0, stream>>>((const uint2*)t1n, (const uint4*)t1s,
                                            row_start, src_sorted, deg_inv, b1, (uint4*)hbf, N);
    // 5. layer 2 GEMM: hbf -> t2s bf16 [Mpad x 64] + t2n fp8 [Mpad x 64] (reuse t1s/t1n)
    int nstrip2 = Mpad / 128;
    gemm_rs<128, 8, false><<<dim3(256, 1), 512, 0, stream>>>(hbf, nstrip2, Wt2, t1s, t1n);
    // 6. aggregate -> out f32
    k_agg2<<<(N + 3) / 4, 256, 0, stream>>>((const uint2*)t1n, (const uint4*)t1s,
                                            row_start, src_sorted, deg_inv, b2, out, N);
}

// Round 10
// 303.843 us; speedup vs baseline: 1.1477x; 1.0613x over previous
//
#include <hip/hip_runtime.h>
#include <hip/hip_bf16.h>

// GraphSAGE 2-layer: radix-bucket CSR build + bf16 MFMA transform-then-aggregate.
// N=100000, E=3.2M, IN=256, H=128, OUT=64.
// CSR: fine hist (dst>>7) -> scan -> coarse scatter (dst>>12, runs ~656B)
//      -> fine scatter (32 fine/coarse, runs ~512B) -> per-bucket sort.
// GEMM: fragment-ordered B in LDS (conflict-free), 8 waves, reg double-buffer.
// Neighbor buffers (t1n/t2n) stored fp8-e4m3 (halved gather traffic).

typedef unsigned int uint32;
typedef __attribute__((ext_vector_type(8))) short short8;
typedef __attribute__((ext_vector_type(4))) float f32x4;

#define NBMAX 1024     // max fine buckets (N <= 131072 at 128 nodes/bucket)
#define NQMAX 32       // max coarse buckets (4096 nodes each)
#define EPB   4096     // edges per block in hist/scatter passes

#if defined(__has_builtin)
#if __has_builtin(__builtin_amdgcn_cvt_pk_f32_fp8) && __has_builtin(__builtin_amdgcn_cvt_pk_fp8_f32)
#define FP8_HW 1
#endif
#endif
#ifndef FP8_HW
#define FP8_HW 0
#endif

__device__ __forceinline__ unsigned short f2bf(float f) {
    unsigned u = __float_as_uint(f);
    u += 0x7fffu + ((u >> 16) & 1u);      // RNE
    return (unsigned short)(u >> 16);
}
__device__ __forceinline__ uint32 pack2bf(float lo, float hi) {
    return (uint32)f2bf(lo) | ((uint32)f2bf(hi) << 16);
}
__device__ __forceinline__ float bf_lo(uint32 v) { return __uint_as_float(v << 16); }
__device__ __forceinline__ float bf_hi(uint32 v) { return __uint_as_float(v & 0xFFFF0000u); }

// ---- fp8 e4m3 encode/decode ----
__device__ __forceinline__ unsigned char enc8(float v) {
#if FP8_HW
    return (unsigned char)(__builtin_amdgcn_cvt_pk_fp8_f32(v, v, 0, false) & 0xFF);
#else
    float g = v * 0x1p-120f;
    uint32 b = __float_as_uint(g);
    uint32 s = (b >> 24) & 0x80u;
    b &= 0x7fffffffu;
    b += 0x7ffffu + ((b >> 20) & 1u);     // RNE to 3 mantissa bits
    int t = (int)(b >> 20) - 960;
    t = t < 0 ? 0 : (t > 126 ? 126 : t);
    return (unsigned char)(s | (uint32)t);
#endif
}
#if !FP8_HW
__device__ __forceinline__ float dec1(uint32 b) {
    uint32 bits = ((b & 0x80u) << 24) | ((b & 0x7fu) << 20);
    return __uint_as_float(bits) * 0x1p+120f;
}
#endif
__device__ __forceinline__ void dec_u32(uint32 u, float& f0, float& f1, float& f2, float& f3) {
#if FP8_HW
    auto lo = __builtin_amdgcn_cvt_pk_f32_fp8(u, false);
    auto hi = __builtin_amdgcn_cvt_pk_f32_fp8(u, true);
    f0 = lo[0]; f1 = lo[1]; f2 = hi[0]; f3 = hi[1];
#else
    f0 = dec1(u & 0xffu); f1 = dec1((u >> 8) & 0xffu);
    f2 = dec1((u >> 16) & 0xffu); f3 = dec1(u >> 24);
#endif
}

// ---------------- pass A: fine histogram (bucket = dst >> 7) ----------------
__global__ __launch_bounds__(256) void k_hist_fine(const int* __restrict__ dst, int E,
                                                   int* __restrict__ bcnt) {
    __shared__ int hist[NBMAX];
    for (int i = threadIdx.x; i < NBMAX; i += 256) hist[i] = 0;
    __syncthreads();
    int base = blockIdx.x * EPB;
    #pragma unroll 4
    for (int i = 0; i < EPB / 256; ++i) {
        int e = base + i * 256 + threadIdx.x;
        if (e < E) atomicAdd(&hist[dst[e] >> 7], 1);
    }
    __syncthreads();
    for (int i = threadIdx.x; i < NBMAX; i += 256) {
        int h = hist[i];
        if (h) atomicAdd(&bcnt[i], h);
    }
}

// ---------------- scan: fine offsets + fills, coarse fills ----------------
__global__ __launch_bounds__(1024) void k_scan(const int* __restrict__ bcnt, int NBF, int NQ,
                                               int* __restrict__ boffs, int* __restrict__ gfill_fine,
                                               int* __restrict__ gfillq, int E) {
    __shared__ int sd[1024];
    int tid = threadIdx.x;
    int v = (tid < NBF) ? bcnt[tid] : 0;
    sd[tid] = v;
    __syncthreads();
    for (int off = 1; off < 1024; off <<= 1) {
        int t = (tid >= off) ? sd[tid - off] : 0;
        __syncthreads();
        sd[tid] += t;
        __syncthreads();
    }
    int excl = sd[tid] - v;
    if (tid < NBF) { boffs[tid] = excl; gfill_fine[tid] = excl; }
    if (tid == 0) boffs[NBF] = E;
    __syncthreads();
    if (tid < NQ) {
        int f = tid * 32;
        gfillq[tid] = (f < NBF) ? (sd[f] - ((f < NBF) ? bcnt[f] : 0)) : E;
    }
}

// ---------------- pass B: coarse scatter (q = dst >> 12) ----------------
// pairs1[pos] = (src << 12) | (dst & 4095); runs ~EPB/NQ edges per (block,q).
__global__ __launch_bounds__(256) void k_scatter_coarse(const int* __restrict__ src,
                                                        const int* __restrict__ dst, int E,
                                                        int* __restrict__ gfillq,
                                                        uint32* __restrict__ pairs1) {
    __shared__ int hist[NQMAX];
    __shared__ int basea[NQMAX];
    if (threadIdx.x < NQMAX) hist[threadIdx.x] = 0;
    __syncthreads();
    int base = blockIdx.x * EPB;
    #pragma unroll 4
    for (int i = 0; i < EPB / 256; ++i) {
        int e = base + i * 256 + threadIdx.x;
        if (e < E) atomicAdd(&hist[dst[e] >> 12], 1);
    }
    __syncthreads();
    if (threadIdx.x < NQMAX) {
        int h = hist[threadIdx.x];
        basea[threadIdx.x] = h ? atomicAdd(&gfillq[threadIdx.x], h) : 0;
        hist[threadIdx.x] = 0;
    }
    __syncthreads();
    #pragma unroll 4
    for (int i = 0; i < EPB / 256; ++i) {
        int e = base + i * 256 + threadIdx.x;
        if (e < E) {
            int d = dst[e];
            int q = d >> 12;
            int pos = basea[q] + atomicAdd(&hist[q], 1);
            pairs1[pos] = ((uint32)src[e] << 12) | (uint32)(d & 4095);
        }
    }
}

// ---------------- pass C: fine scatter within coarse segments ----------------
__global__ __launch_bounds__(256) void k_scatter_fine(const uint32* __restrict__ pairs1,
                                                      const int* __restrict__ boffs,
                                                      const int* __restrict__ qend,
                                                      int* __restrict__ gfill_fine,
                                                      uint32* __restrict__ pairs2, int NC) {
    __shared__ int hist[32];
    __shared__ int basea[32];
    const int q = blockIdx.x;
    const int s0 = boffs[q * 32];
    const int s1 = qend[q];
    for (long cb = (long)s0 + (long)blockIdx.y * EPB; cb < s1; cb += (long)NC * EPB) {
        int cend = (int)((cb + EPB < s1) ? cb + EPB : s1);
        if (threadIdx.x < 32) hist[threadIdx.x] = 0;
        __syncthreads();
        for (int e = (int)cb + threadIdx.x; e < cend; e += 256)
            atomicAdd(&hist[(pairs1[e] >> 7) & 31], 1);
        __syncthreads();
        if (threadIdx.x < 32) {
            int h = hist[threadIdx.x];
            basea[threadIdx.x] = h ? atomicAdd(&gfill_fine[q * 32 + threadIdx.x], h) : 0;
            hist[threadIdx.x] = 0;
        }
        __syncthreads();
        for (int e = (int)cb + threadIdx.x; e < cend; e += 256) {
            uint32 p = pairs1[e];
            int fl = (p >> 7) & 31;
            int pos = basea[fl] + atomicAdd(&hist[fl], 1);
            pairs2[pos] = p;
        }
        __syncthreads();
    }
}

// ---------------- pass D: per-fine-bucket sort -> CSR ----------------
__global__ __launch_bounds__(256) void k_bucket_sort(const uint32* __restrict__ pairs,
                                                     const int* __restrict__ boffs,
                                                     int N, int E,
                                                     int* __restrict__ row_start,
                                                     float* __restrict__ deg_inv,
                                                     int* __restrict__ src_sorted) {
    __shared__ int cnt[128];
    __shared__ int sc[128];
    __shared__ int fill[128];
    int b = blockIdx.x, tid = threadIdx.x;
    int s0 = boffs[b], s1 = boffs[b + 1];
    if (tid < 128) cnt[tid] = 0;
    __syncthreads();
    for (int e = s0 + tid; e < s1; e += 256)
        atomicAdd(&cnt[pairs[e] & 127], 1);
    __syncthreads();
    if (tid < 128) sc[tid] = cnt[tid];
    __syncthreads();
    for (int off = 1; off < 128; off <<= 1) {
        int v = 0;
        if (tid < 128 && tid >= off) v = sc[tid - off];
        __syncthreads();
        if (tid < 128) sc[tid] += v;
        __syncthreads();
    }
    if (tid < 128) {
        int excl = sc[tid] - cnt[tid];
        int node = b * 128 + tid;
        if (node < N) {
            row_start[node] = s0 + excl;
            int d = cnt[tid];
            deg_inv[node] = 1.0f / (float)(d > 1 ? d : 1);
        }
        fill[tid] = s0 + excl;
    }
    if (b == 0 && tid == 0) row_start[N] = E;
    __syncthreads();
    for (int e = s0 + tid; e < s1; e += 256) {
        uint32 p = pairs[e];
        int pos = atomicAdd(&fill[p & 127], 1);
        src_sorted[pos] = (int)(p >> 12);
    }
}

// ---------------- x f32 -> bf16 pre-cast (zero-fills pad rows) ----------------
__global__ __launch_bounds__(256) void k_cast_x(const float* __restrict__ x, uint32* __restrict__ xb,
                                                long n8, long total8) {
    long t = (long)blockIdx.x * blockDim.x + threadIdx.x;
    if (t >= total8) return;
    uint4 o = make_uint4(0u, 0u, 0u, 0u);
    if (t < n8) {
        const float4* p = reinterpret_cast<const float4*>(x) + t * 2;
        float4 a = p[0], b = p[1];
        o.x = pack2bf(a.x, a.y); o.y = pack2bf(a.z, a.w);
        o.z = pack2bf(b.x, b.y); o.w = pack2bf(b.z, b.w);
    }
    reinterpret_cast<uint4*>(xb)[t] = o;
}

// transpose+cast weights: Wt[c][k] = (c<halfC ? Ws[k][c] : Wn[k][c-halfC]), row-major [2*halfC][K]
__global__ __launch_bounds__(256) void k_wt(const float* __restrict__ Ws, const float* __restrict__ Wn,
                                            int K, int logK, int halfC, unsigned short* __restrict__ Wt) {
    int t = blockIdx.x * blockDim.x + threadIdx.x;
    int total = 2 * halfC * K;
    if (t >= total) return;
    int c = t >> logK, k = t & (K - 1);
    float v = (c < halfC) ? Ws[(size_t)k * halfC + c] : Wn[(size_t)k * halfC + (c - halfC)];
    Wt[t] = f2bf(v);
}

// ---------------- register-streaming MFMA GEMM, fragment-ordered B in LDS ----------------
template<int K, int NF, bool YSPLIT>
__global__ __launch_bounds__(512) void gemm_rs(const unsigned short* __restrict__ A, int nstrip,
                                               const unsigned short* __restrict__ Wt,
                                               unsigned short* __restrict__ S16,
                                               unsigned char* __restrict__ N8) {
    constexpr int KS = K / 32;
    __shared__ unsigned short Bs[NF * KS * 512];
    const int tid = threadIdx.x;
    const int wave = tid >> 6, lane = tid & 63;
    const int l15 = lane & 15, l4 = lane >> 4;

    const unsigned short* Wtblk = Wt + (YSPLIT ? (size_t)blockIdx.y * 128 * K : 0);
    const bool out8 = YSPLIT && (blockIdx.y == 1);

    for (int i = tid; i < NF * KS * 64; i += 512) {
        int f = i >> 6, l = i & 63;
        int s = f / NF, n = f - s * NF;
        int col = n * 16 + (l & 15);
        int k = s * 32 + (l >> 4) * 8;
        uint4 v = *reinterpret_cast<const uint4*>(&Wtblk[(size_t)col * K + k]);
        *reinterpret_cast<uint4*>(&Bs[(size_t)i * 8]) = v;
    }
    __syncthreads();

    const unsigned short* Bl = Bs + (size_t)lane * 8;
    const int stride = gridDim.x;
    int g = blockIdx.x;
    if (g >= nstrip) return;

    uint4 uA[KS], uB[KS];

    auto loadA = [&](int gg, uint4* u) {
        int arow = gg * 128 + wave * 16 + l15;
        const unsigned short* Ar = A + (size_t)arow * K + l4 * 8;
        #pragma unroll
        for (int s = 0; s < KS; ++s)
            u[s] = *reinterpret_cast<const uint4*>(Ar + s * 32);
    };

    auto compute = [&](int gc, uint4* u) {
        f32x4 acc[NF] = {};
        #pragma unroll
        for (int s = 0; s < KS; ++s) {
            union { uint4 q; short8 v; } cv;
            cv.q = u[s];
            short8 af = cv.v;
            #pragma unroll
            for (int n = 0; n < NF; ++n) {
                short8 bf = *reinterpret_cast<const short8*>(Bl + (size_t)(s * NF + n) * 512);
                acc[n] = __builtin_amdgcn_mfma_f32_16x16x32_bf16(af, bf, acc[n], 0, 0, 0);
            }
        }
        const int rbase = gc * 128 + wave * 16;
        #pragma unroll
        for (int n = 0; n < NF; ++n) {
            #pragma unroll
            for (int r = 0; r < 4; ++r) {
                int rw = rbase + l4 * 4 + r;
                if constexpr (YSPLIT) {
                    int col = n * 16 + l15;
                    if (out8) N8[(size_t)rw * 128 + col] = enc8(acc[n][r]);
                    else      S16[(size_t)rw * 128 + col] = f2bf(acc[n][r]);
                } else {
                    if (n < 4) S16[(size_t)rw * 64 + n * 16 + l15] = f2bf(acc[n][r]);
                    else       N8[(size_t)rw * 64 + (n - 4) * 16 + l15] = enc8(acc[n][r]);
                }
            }
        }
    };

    loadA(g, uA);
    while (true) {
        int gn = g + stride;
        if (gn < nstrip) loadA(gn, uB);
        compute(g, uA);
        if (gn >= nstrip) break;
        g = gn;
        gn = g + stride;
        if (gn < nstrip) loadA(gn, uA);
        compute(g, uB);
        if (gn >= nstrip) break;
        g = gn;
    }
}

// ---------------- layer-1 aggregate + combine + relu -> h (bf16) ----------------
__global__ __launch_bounds__(256) void k_agg1(const uint2* __restrict__ t1n, const uint4* __restrict__ t1s,
                                              const int* __restrict__ rs, const int* __restrict__ ss,
                                              const float* __restrict__ dinv, const float* __restrict__ b1,
                                              uint4* __restrict__ h, int N) {
    int wid  = (blockIdx.x * blockDim.x + threadIdx.x) >> 6;
    int lane = threadIdx.x & 63;
    if (wid >= N) return;
    int e0 = rs[wid], e1 = rs[wid + 1];
    const int q = lane >> 4, c = lane & 15;
    float a0 = 0, a1 = 0, a2 = 0, a3 = 0, a4 = 0, a5 = 0, a6 = 0, a7 = 0;
    float f0, f1, f2, f3;
    int e = e0;
    for (; e + 16 <= e1; e += 16) {
        int s0 = ss[e + q];
        int s1 = ss[e + 4 + q];
        int s2 = ss[e + 8 + q];
        int s3 = ss[e + 12 + q];
        uint2 v0 = t1n[(size_t)s0 * 16 + c];
        uint2 v1 = t1n[(size_t)s1 * 16 + c];
        uint2 v2 = t1n[(size_t)s2 * 16 + c];
        uint2 v3 = t1n[(size_t)s3 * 16 + c];
        dec_u32(v0.x, f0, f1, f2, f3); a0 += f0; a1 += f1; a2 += f2; a3 += f3;
        dec_u32(v0.y, f0, f1, f2, f3); a4 += f0; a5 += f1; a6 += f2; a7 += f3;
        dec_u32(v1.x, f0, f1, f2, f3); a0 += f0; a1 += f1; a2 += f2; a3 += f3;
        dec_u32(v1.y, f0, f1, f2, f3); a4 += f0; a5 += f1; a6 += f2; a7 += f3;
        dec_u32(v2.x, f0, f1, f2, f3); a0 += f0; a1 += f1; a2 += f2; a3 += f3;
        dec_u32(v2.y, f0, f1, f2, f3); a4 += f0; a5 += f1; a6 += f2; a7 += f3;
        dec_u32(v3.x, f0, f1, f2, f3); a0 += f0; a1 += f1; a2 += f2; a3 += f3;
        dec_u32(v3.y, f0, f1, f2, f3); a4 += f0; a5 += f1; a6 += f2; a7 += f3;
    }
    for (; e < e1; e += 4) {
        if (e + q < e1) {
            int s = ss[e + q];
            uint2 v = t1n[(size_t)s * 16 + c];
            dec_u32(v.x, f0, f1, f2, f3); a0 += f0; a1 += f1; a2 += f2; a3 += f3;
            dec_u32(v.y, f0, f1, f2, f3); a4 += f0; a5 += f1; a6 += f2; a7 += f3;
        }
    }
    a0 += __shfl_xor(a0, 16); a1 += __shfl_xor(a1, 16); a2 += __shfl_xor(a2, 16); a3 += __shfl_xor(a3, 16);
    a4 += __shfl_xor(a4, 16); a5 += __shfl_xor(a5, 16); a6 += __shfl_xor(a6, 16); a7 += __shfl_xor(a7, 16);
    a0 += __shfl_xor(a0, 32); a1 += __shfl_xor(a1, 32); a2 += __shfl_xor(a2, 32); a3 += __shfl_xor(a3, 32);
    a4 += __shfl_xor(a4, 32); a5 += __shfl_xor(a5, 32); a6 += __shfl_xor(a6, 32); a7 += __shfl_xor(a7, 32);
    if (lane < 16) {
        float di = dinv[wid];
        uint4 sv = t1s[(size_t)wid * 16 + c];
        float4 bA = *reinterpret_cast<const float4*>(&b1[c * 8]);
        float4 bB = *reinterpret_cast<const float4*>(&b1[c * 8 + 4]);
        float h0 = fmaxf(fmaf(a0, di, bf_lo(sv.x)) + bA.x, 0.f);
        float h1 = fmaxf(fmaf(a1, di, bf_hi(sv.x)) + bA.y, 0.f);
        float h2 = fmaxf(fmaf(a2, di, bf_lo(sv.y)) + bA.z, 0.f);
        float h3 = fmaxf(fmaf(a3, di, bf_hi(sv.y)) + bA.w, 0.f);
        float h4 = fmaxf(fmaf(a4, di, bf_lo(sv.z)) + bB.x, 0.f);
        float h5 = fmaxf(fmaf(a5, di, bf_hi(sv.z)) + bB.y, 0.f);
        float h6 = fmaxf(fmaf(a6, di, bf_lo(sv.w)) + bB.z, 0.f);
        float h7 = fmaxf(fmaf(a7, di, bf_hi(sv.w)) + bB.w, 0.f);
        uint4 o;
        o.x = pack2bf(h0, h1); o.y = pack2bf(h2, h3);
        o.z = pack2bf(h4, h5); o.w = pack2bf(h6, h7);
        h[(size_t)wid * 16 + c] = o;
    }
}

// ---------------- layer-2 aggregate + combine -> out (f32) ----------------
__global__ __launch_bounds__(256) void k_agg2(const uint2* __restrict__ t2n, const uint4* __restrict__ t2s,
                                              const int* __restrict__ rs, const int* __restrict__ ss,
                                              const float* __restrict__ dinv, const float* __restrict__ b2,
                                              float* __restrict__ out, int N) {
    int wid  = (blockIdx.x * blockDim.x + threadIdx.x) >> 6;
    int lane = threadIdx.x & 63;
    if (wid >= N) return;
    int e0 = rs[wid], e1 = rs[wid + 1];
    const int o8 = lane >> 3, c = lane & 7;
    float a0 = 0, a1 = 0, a2 = 0, a3 = 0, a4 = 0, a5 = 0, a6 = 0, a7 = 0;
    float f0, f1, f2, f3;
    int e = e0;
    for (; e + 32 <= e1; e += 32) {
        int s0 = ss[e + o8];
        int s1 = ss[e + 8 + o8];
        int s2 = ss[e + 16 + o8];
        int s3 = ss[e + 24 + o8];
        uint2 v0 = t2n[(size_t)s0 * 8 + c];
        uint2 v1 = t2n[(size_t)s1 * 8 + c];
        uint2 v2 = t2n[(size_t)s2 * 8 + c];
        uint2 v3 = t2n[(size_t)s3 * 8 + c];
        dec_u32(v0.x, f0, f1, f2, f3); a0 += f0; a1 += f1; a2 += f2; a3 += f3;
        dec_u32(v0.y, f0, f1, f2, f3); a4 += f0; a5 += f1; a6 += f2; a7 += f3;
        dec_u32(v1.x, f0, f1, f2, f3); a0 += f0; a1 += f1; a2 += f2; a3 += f3;
        dec_u32(v1.y, f0, f1, f2, f3); a4 += f0; a5 += f1; a6 += f2; a7 += f3;
        dec_u32(v2.x, f0, f1, f2, f3); a0 += f0; a1 += f1; a2 += f2; a3 += f3;
        dec_u32(v2.y, f0, f1, f2, f3); a4 += f0; a5 += f1; a6 += f2; a7 += f3;
        dec_u32(v3.x, f0, f1, f2, f3); a0 += f0; a1 += f1; a2 += f2; a3 += f3;
        dec_u32(v3.y, f0, f1, f2, f3); a4 += f0; a5 += f1; a6 += f2; a7 += f3;
    }
    for (; e < e1; e += 8) {
        if (e + o8 < e1) {
            int s = ss[e + o8];
            uint2 v = t2n[(size_t)s * 8 + c];
            dec_u32(v.x, f0, f1, f2, f3); a0 += f0; a1 += f1; a2 += f2; a3 += f3;
            dec_u32(v.y, f0, f1, f2, f3); a4 += f0; a5 += f1; a6 += f2; a7 += f3;
        }
    }
    a0 += __shfl_xor(a0, 8);  a1 += __shfl_xor(a1, 8);  a2 += __shfl_xor(a2, 8);  a3 += __shfl_xor(a3, 8);
    a4 += __shfl_xor(a4, 8);  a5 += __shfl_xor(a5, 8);  a6 += __shfl_xor(a6, 8);  a7 += __shfl_xor(a7, 8);
    a0 += __shfl_xor(a0, 16); a1 += __shfl_xor(a1, 16); a2 += __shfl_xor(a2, 16); a3 += __shfl_xor(a3, 16);
    a4 += __shfl_xor(a4, 16); a5 += __shfl_xor(a5, 16); a6 += __shfl_xor(a6, 16); a7 += __shfl_xor(a7, 16);
    a0 += __shfl_xor(a0, 32); a1 += __shfl_xor(a1, 32); a2 += __shfl_xor(a2, 32); a3 += __shfl_xor(a3, 32);
    a4 += __shfl_xor(a4, 32); a5 += __shfl_xor(a5, 32); a6 += __shfl_xor(a6, 32); a7 += __shfl_xor(a7, 32);
    if (lane < 8) {
        float di = dinv[wid];
        uint4 sv = t2s[(size_t)wid * 8 + c];
        float4 bA = *reinterpret_cast<const float4*>(&b2[c * 8]);
        float4 bB = *reinterpret_cast<const float4*>(&b2[c * 8 + 4]);
        float4 oA, oB;
        oA.x = fmaf(a0, di, bf_lo(sv.x)) + bA.x;
        oA.y = fmaf(a1, di, bf_hi(sv.x)) + bA.y;
        oA.z = fmaf(a2, di, bf_lo(sv.y)) + bA.z;
        oA.w = fmaf(a3, di, bf_hi(sv.y)) + bA.w;
        oB.x = fmaf(a4, di, bf_lo(sv.z)) + bB.x;
        oB.y = fmaf(a5, di, bf_hi(sv.z)) + bB.y;
        oB.z = fmaf(a6, di, bf_lo(sv.w)) + bB.z;
        oB.w = fmaf(a7, di, bf_hi(sv.w)) + bB.w;
        *reinterpret_cast<float4*>(&out[(size_t)wid * 64 + c * 8]) = oA;
        *reinterpret_cast<float4*>(&out[(size_t)wid * 64 + c * 8 + 4]) = oB;
    }
}

extern "C" void kernel_launch(void* const* d_in, const int* in_sizes, int n_in,
                              void* d_out, int out_size, void* d_ws, size_t ws_size,
                              hipStream_t stream) {
    const float* x   = (const float*)d_in[0];
    const int*   src = (const int*)d_in[1];
    const int*   dst = (const int*)d_in[2];
    const float* W1s = (const float*)d_in[3];
    const float* W1n = (const float*)d_in[4];
    const float* b1  = (const float*)d_in[5];
    const float* W2s = (const float*)d_in[6];
    const float* W2n = (const float*)d_in[7];
    const float* b2  = (const float*)d_in[8];
    float* out = (float*)d_out;

    const int IN = 256, H = 128, OUT = 64;
    const int N  = in_sizes[0] / IN;
    const int E  = in_sizes[1];
    const int Mpad = (N + 127) & ~127;
    const int NBF = (N + 127) >> 7;       // fine buckets (128 nodes)
    const int NQ  = (N + 4095) >> 12;     // coarse buckets (4096 nodes)

    char* ws = (char*)d_ws;
    size_t off = 0;
    auto alloc = [&](size_t bytes) -> char* {
        char* p = ws + off;
        off = (off + bytes + 255) & ~(size_t)255;
        return p;
    };
    int*   row_start  = (int*)  alloc((size_t)(N + 1) * 4);
    float* deg_inv    = (float*)alloc((size_t)N * 4);
    int*   bcnt       = (int*)  alloc((size_t)NBMAX * 4);
    int*   boffs      = (int*)  alloc((size_t)(NBMAX + 1) * 4);
    int*   gfill_fine = (int*)  alloc((size_t)NBMAX * 4);
    int*   gfillq     = (int*)  alloc((size_t)NQMAX * 4);
    int*   src_sorted = (int*)  alloc((size_t)E * 4);
    uint32* pairs1    = (uint32*)alloc((size_t)E * 4);
    uint32* pairs2    = (uint32*)alloc((size_t)E * 4);
    unsigned short* xb  = (unsigned short*)alloc((size_t)Mpad * IN * 2);  // bf16 x (pad rows zero)
    unsigned short* Wt1 = (unsigned short*)alloc((size_t)(2 * H) * IN * 2);
    unsigned short* Wt2 = (unsigned short*)alloc((size_t)(2 * OUT) * H * 2);
    unsigned short* t1s = (unsigned short*)alloc((size_t)Mpad * H * 2);  // bf16 self; reused as t2s (ld 64)
    unsigned char*  t1n = (unsigned char*) alloc((size_t)Mpad * H);     // fp8 neigh; reused as t2n (ld 64)
    unsigned short* hbf = (unsigned short*)alloc((size_t)Mpad * H * 2); // layer-1 output (bf16)

    // 1. CSR build: fine hist -> scan -> coarse scatter -> fine scatter -> bucket sort
    hipMemsetAsync(bcnt, 0, (size_t)NBMAX * 4, stream);
    int nblk = (E + EPB - 1) / EPB;
    k_hist_fine     <<<nblk, 256, 0, stream>>>(dst, E, bcnt);
    k_scan          <<<1, 1024, 0, stream>>>(bcnt, NBF, NQ, boffs, gfill_fine, gfillq, E);
    k_scatter_coarse<<<nblk, 256, 0, stream>>>(src, dst, E, gfillq, pairs1);
    k_scatter_fine  <<<dim3(NQ, 32), 256, 0, stream>>>(pairs1, boffs, gfillq, gfill_fine, pairs2, 32);
    k_bucket_sort   <<<NBF, 256, 0, stream>>>(pairs2, boffs, N, E, row_start, deg_inv, src_sorted);

    // 2. casts: x -> bf16 (pad rows zero), weights transpose+cast
    long n8 = (long)N * IN / 8, total8 = (long)Mpad * IN / 8;
    k_cast_x<<<(int)((total8 + 255) / 256), 256, 0, stream>>>(x, (uint32*)xb, n8, total8);
    k_wt<<<(2 * H * IN + 255) / 256, 256, 0, stream>>>(W1s, W1n, IN, 8, H, Wt1);
    k_wt<<<(2 * OUT * H + 255) / 256, 256, 0, stream>>>(W2s, W2n, H, 7, OUT, Wt2);

    // 3. layer 1 GEMM: xb -> t1s bf16 [Mpad x 128] (y=0), t1n fp8 [Mpad x 128] (y=1)
    int nstrip1 = Mpad / 128;
    gemm_rs<256, 8, true><<<dim3(256, 2), 512, 0, stream>>>(xb, nstrip1, Wt1, t1s, t1n);
    // 4. aggregate + relu -> h bf16
    k_agg1<<<(N + 3) / 4, 256, 0, stream>>>((const uint2*)t1n, (const uint4*)t1s,
                                            row_start, src_sorted, deg_inv, b1, (uint4*)hbf, N);
    // 5. layer 2 GEMM: hbf -> t2s bf16 [Mpad x 64] + t2n fp8 [Mpad x 64] (reuse t1s/t1n)
    int nstrip2 = Mpad / 128;
    gemm_rs<128, 8, false><<<dim3(256, 1), 512, 0, stream>>>(hbf, nstrip2, Wt2, t1s, t1n);
    // 6. aggregate -> out f32
    k_agg2<<<(N + 3) / 4, 256, 0, stream>>>((const uint2*)t1n, (const uint4*)t1s,
                                            row_start, src_sorted, deg_inv, b2, out, N);
}